// Round 4
// baseline (129.556 us; speedup 1.0000x reference)
//
#include <hip/hip_runtime.h>

// B=64, K=8, H=W=128 (HW=16384). float32 in/out.
// out[0] = loss scalar; out[1..] = pred_perm (B,K,H,W) flat.
//
// Pipeline (2 kernels + one 4-byte memset):
//   cost_kernel    : LDS-staged partial sums of cross[i][j] = sum_hw t_j*log(p_i+eps)
//                    and ent[j] = sum_hw t_j*log(t_j+eps); async global->LDS staging
//                    (global_load_lds, 16B), disjoint output slots, no atomics.
//   permute_kernel : every block redundantly reduces its batch's partials + runs the
//                    Held-Karp DP, then copies its half-row with float4 stores;
//                    one block per batch atomicAdds the loss into out[0].

#define BB 64
#define KK 8
#define HW 16384
#define CH 64        // chunks per batch for cost_kernel
#define CHUNK 256    // floats per chunk
#define EPSF 1e-15f

// ---------- compile-time mask table: all 255 nonzero 8-bit masks, level-ordered by popcount ----------
struct MaskTab {
    unsigned char masks[255];
    int off[9];
};

constexpr MaskTab make_tab() {
    MaskTab t{};
    int idx = 0;
    for (int p = 1; p <= 8; ++p) {
        t.off[p - 1] = idx;
        for (int m = 1; m < 256; ++m) {
            int c = 0;
            for (int b = 0; b < 8; ++b) c += (m >> b) & 1;
            if (c == p) t.masks[idx++] = (unsigned char)m;
        }
    }
    t.off[8] = idx;
    return t;
}

__constant__ MaskTab kTab = make_tab();

__device__ __forceinline__ float dot4(float4 t, float4 l) {
    return t.x * l.x + t.y * l.y + t.z * l.z + t.w * l.w;
}

__device__ __forceinline__ float4 log4(float4 a) {
    float4 r;
    r.x = __logf(a.x + EPSF); r.y = __logf(a.y + EPSF);
    r.z = __logf(a.z + EPSF); r.w = __logf(a.w + EPSF);
    return r;
}

// ---------- phase 1: partial cross/ent sums, LDS-staged ----------
// grid: B*CH blocks of 256 threads (4 waves). Block stages a 256-float chunk of all
// 16 rows (pred 0-7 -> tile rows 0-7, aug 0-7 -> tile rows 8-15) via async
// global_load_lds (wave w, step m loads virtual row w+4m: wave-uniform LDS base +
// lane*16B, per the gfx950 constraint). Then wave w computes cross rows {2w,2w+1}
// and ent rows {2w,2w+1} entirely from LDS. 16KB LDS, ~8 blocks/CU resident.
__global__ __launch_bounds__(256) void cost_kernel(const float* __restrict__ pred,
                                                   const float* __restrict__ aug,
                                                   float* __restrict__ part)   // [B*CH][72]
{
    __shared__ float tile[16][CHUNK];

    const int blk   = blockIdx.x;        // b*CH + chunk
    const int b     = blk >> 6;
    const int chunk = blk & 63;
    const int tid   = threadIdx.x;
    const int wave  = tid >> 6;
    const int lane  = tid & 63;

    const size_t base = (size_t)b * (KK * HW) + (size_t)chunk * CHUNK;

#pragma unroll
    for (int m = 0; m < 4; ++m) {
        const int vr = wave + 4 * m;     // virtual row 0..15, wave-uniform
        const float* g = ((vr < 8) ? (pred + base + (size_t)vr * HW)
                                   : (aug  + base + (size_t)(vr - 8) * HW)) + lane * 4;
        __builtin_amdgcn_global_load_lds(
            (const __attribute__((address_space(1))) void*)g,
            (__attribute__((address_space(3))) void*)&tile[vr][lane * 4],
            16, 0, 0);
    }
    __syncthreads();   // compiler drains vmcnt before s_barrier

    const int w2 = 2 * wave;
    const int e4 = lane * 4;

    const float4 p0 = *(const float4*)&tile[w2][e4];
    const float4 p1 = *(const float4*)&tile[w2 + 1][e4];
    const float4 la = log4(p0);
    const float4 lc = log4(p1);
    const float4 t0 = *(const float4*)&tile[8 + w2][e4];
    const float4 t1 = *(const float4*)&tile[8 + w2 + 1][e4];
    float e0 = dot4(t0, log4(t0));
    float e1 = dot4(t1, log4(t1));

    float acc[16];
#pragma unroll
    for (int j = 0; j < 8; ++j) {
        const float4 tv = *(const float4*)&tile[8 + j][e4];
        acc[j]     = dot4(tv, la);
        acc[8 + j] = dot4(tv, lc);
    }

    // wave-wide butterfly reduce: 18 values
#pragma unroll
    for (int v = 0; v < 16; ++v) {
        float s = acc[v];
#pragma unroll
        for (int d = 1; d < 64; d <<= 1) s += __shfl_xor(s, d);
        acc[v] = s;
    }
#pragma unroll
    for (int d = 1; d < 64; d <<= 1) e0 += __shfl_xor(e0, d);
#pragma unroll
    for (int d = 1; d < 64; d <<= 1) e1 += __shfl_xor(e1, d);

    if (lane == 0) {
        float* dst = part + (size_t)blk * 72;
#pragma unroll
        for (int j = 0; j < 8; ++j) {
            dst[16 * wave + j]     = acc[j];       // cross[i=2w][j]
            dst[16 * wave + 8 + j] = acc[8 + j];   // cross[i=2w+1][j]
        }
        dst[64 + w2]     = e0;                     // ent[2w]
        dst[64 + w2 + 1] = e1;                     // ent[2w+1]
    }
}

// ---------- phase 2: fused DP + permuted copy ----------
// grid: 1024 blocks of 256 threads; block g handles half of pair p=g>>1 (half=g&1).
// Every block redundantly reduces partials for b=p>>3 and runs the Held-Karp DP
// (parallel, ~µs). Block g==16b also adds the batch loss to out[0].
// Stores: out+1 row base is 4B-aligned; element 3 of each row is 16B-aligned, so
// middle 4095 quads go out as float4; head 3 + tail 1 elements scalar (one thread).
__global__ __launch_bounds__(256) void permute_kernel(const float* __restrict__ pred,
                                                      const float* __restrict__ part,
                                                      float* __restrict__ out)
{
    __shared__ float red[72];
    __shared__ float C[64];     // C[i*8+j] = ent[j] - cross[i][j] (unscaled)
    __shared__ float dp[256];
    __shared__ int   choice[256];
    __shared__ int   inv8[8];   // col -> src row

    const int g    = blockIdx.x;
    const int p    = g >> 1;       // pair = b*8 + jcol
    const int half = g & 1;
    const int b    = p >> 3;
    const int tid  = threadIdx.x;

    // --- reduce partials for batch b ---
    const float* pb = part + (size_t)b * CH * 72;
    if (tid < 72) {
        float s = 0.f;
#pragma unroll
        for (int c = 0; c < CH; ++c) s += pb[c * 72 + tid];
        red[tid] = s;
    }
    __syncthreads();
    if (tid < 64) C[tid] = red[64 + (tid & 7)] - red[tid];
    if (tid == 0) dp[0] = 0.f;
    __syncthreads();

    // --- Held-Karp DP over 255 masks, level-ordered by popcount ---
    const int grp = tid >> 3;      // 32 mask slots per pass
    const int j   = tid & 7;

    for (int lvl = 1; lvl <= 8; ++lvl) {
        const int start = kTab.off[lvl - 1];
        const int end   = kTab.off[lvl];
        const float* Crow = &C[(lvl - 1) * 8];
        for (int base = start; base < end; base += 32) {
            const int mi = base + grp;
            if (mi < end) {
                const int M = kTab.masks[mi];
                float v  = 1e30f;
                int   bj = 0;
                if (M & (1 << j)) {
                    v  = dp[M ^ (1 << j)] + Crow[j];
                    bj = j;
                }
#pragma unroll
                for (int d = 1; d < 8; d <<= 1) {
                    float ov = __shfl_xor(v, d);
                    int   oj = __shfl_xor(bj, d);
                    if (ov < v) { v = ov; bj = oj; }
                }
                if (j == 0) { dp[M] = v; choice[M] = bj; }
            }
        }
        __syncthreads();
    }

    if (tid == 0) {
        int mask = 255;
        for (int r = 7; r >= 0; --r) {
            const int jj = choice[mask];
            inv8[jj] = r;              // column jj takes pred row r
            mask ^= 1 << jj;
        }
        if (g == (b << 4))             // exactly one block per batch
            atomicAdd(out, dp[255] * (1.0f / (16384.0f * 512.0f)));
    }
    __syncthreads();

    // --- permuted copy of half a row (8192 elements = 2048 quads) ---
    const int src_row = inv8[p & 7];   // uniform per block
    const float* src = pred + ((size_t)(b << 3) + src_row) * HW;
    float*       drow = out + 1 + (size_t)p * HW;

#pragma unroll
    for (int m = 0; m < 8; ++m) {
        const int f = half * 2048 + tid + 256 * m;   // quad index in [0,4096)
        const int e = 3 + 4 * f;
        if (f < 4095) {
            float4 v;
            v.x = src[e]; v.y = src[e + 1]; v.z = src[e + 2]; v.w = src[e + 3];
            *(float4*)(drow + e) = v;                // 16B-aligned: 1+3+4f ≡ 0 mod 4
        } else {                                     // f==4095: head 3 + tail 1
            drow[0] = src[0]; drow[1] = src[1]; drow[2] = src[2];
            drow[16383] = src[16383];
        }
    }
}

extern "C" void kernel_launch(void* const* d_in, const int* in_sizes, int n_in,
                              void* d_out, int out_size, void* d_ws, size_t ws_size,
                              hipStream_t stream) {
    const float* pred = (const float*)d_in[0];
    const float* aug  = (const float*)d_in[1];
    float* out = (float*)d_out;
    float* part = (float*)d_ws;                      // 64*64*72 floats = 1.2 MB

    hipMemsetAsync(d_out, 0, sizeof(float), stream); // zero the loss accumulator

    cost_kernel<<<dim3(BB * CH), dim3(256), 0, stream>>>(pred, aug, part);
    permute_kernel<<<dim3(1024), dim3(256), 0, stream>>>(pred, part, out);
}